// Round 7
// baseline (4094.966 us; speedup 1.0000x reference)
//
#include <hip/hip_runtime.h>
#include <hip/hip_bf16.h>
#include <stdint.h>

typedef __hip_bfloat16 bf16_t;
typedef __attribute__((ext_vector_type(8))) short bf16x8;
typedef __attribute__((ext_vector_type(16))) float f32x16;

#define MU_DT 0.01f

__device__ inline void gload_lds16(const void* g, void* lds) {
  __builtin_amdgcn_global_load_lds((const __attribute__((address_space(1))) void*)g,
                                   (__attribute__((address_space(3))) void*)lds, 16, 0, 0);
}

// mode: 0 = forward tanh layer, 1 = forward identity (last) layer,
//       2 = backward layer 0 (e0 == mu0), 3 = backward layer >0
struct GemmLayer {
  const bf16_t* A;    // (512 x K) bf16, row-major
  const bf16_t* Bt;   // (N x K) bf16, row-major  ("B^T layout" operand)
  const float*  X;    // fwd: mu_{l+1} or img (512 x N); bwd: mu_l (512 x N)
  const float*  E;    // bwd l>0: e_l (512 x N); else unused
  float*        O1;   // fwd: e_{l+1} out (stride ostride); bwd: mu_l out (f32)
  bf16_t*       O2;   // fwd: G_l out (bf16, 512 x N); bwd: mub_l out (bf16)
  int K, N, ostride, mode;
};

struct GemmArgs {
  GemmLayer L[3];
  int start1, start2;     // flat block-id starts of layer 1 and layer 2
  int tn0, tn1, tn2;      // tiles along N per layer
};

// BM=128 x BN=128, BK=64, 32x32x16 MFMA (2x FLOP per LDS byte vs 16x16x32),
// per-wave 64x64 output (2x2 of 32x32, f32x16 acc). Double-buffered LDS,
// R4 schedule: issue next-tile global_load_lds FIRST, then ds_read+MFMA on
// current half, then ONE __syncthreads (drains vmcnt+lgkm) per K-step.
//
// Grid mapping: local = tm*tilesN + tn (tn FASTEST). With round-robin
// block->XCD dispatch (XCD = bid%8), the M-tile sharers of B-panel tn are
// all congruent to tn mod 8 (tilesN multiple of 8) -> SAME XCD -> B-panel
// fetched once per XCD L2. (R5's tm-fastest tripled FETCH_SIZE. Keep this.)
//
// Swizzle: LDS rows 128B = 8 x 16B slots, slot ^= (row&7), applied on the
// global SOURCE address (LDS stays linear for global_load_lds) and again on
// the ds_read side (rule #21: both-sides-or-neither).
__global__ __launch_bounds__(256) void gemm_merged(GemmArgs args) {
  __shared__ __align__(16) bf16_t As[2 * 128 * 64];   // 2 x 16 KiB
  __shared__ __align__(16) bf16_t Bs[2 * 128 * 64];   // 2 x 16 KiB

  const int bid = blockIdx.x;
  int l, local, tilesN;
  if (bid >= args.start2)      { l = 2; local = bid - args.start2; tilesN = args.tn2; }
  else if (bid >= args.start1) { l = 1; local = bid - args.start1; tilesN = args.tn1; }
  else                         { l = 0; local = bid;               tilesN = args.tn0; }
  const GemmLayer Lr = args.L[l];
  const int tm = local / tilesN;
  const int tn = local % tilesN;
  const int K = Lr.K;
  const int rowBase = tm * 128;
  const int colBase = tn * 128;

  const int tid  = threadIdx.x;
  const int lane = tid & 63;
  const int wv   = tid >> 6;
  const int wr   = wv >> 1, wc = wv & 1;   // 2x2 waves, each owns 64x64 out
  const int lo5  = lane & 31;              // row/col within 32-tile
  const int g    = lane >> 5;              // k-group (0/1) for 32x32x16 frags

  f32x16 acc[2][2];
#pragma unroll
  for (int m = 0; m < 2; ++m)
#pragma unroll
    for (int n = 0; n < 2; ++n)
      acc[m][n] = (f32x16)(0.0f);

  char* AsB = (char*)As;   // halves at +0 / +16384
  char* BsB = (char*)Bs;   // halves at +0 / +16384

  // ---- staging precompute: per 16B-chunk c -> (row = c>>3, slot = c&7) ----
  // tile is [128 rows][64 k] bf16 = 1024 chunks; 256 threads x 4 chunks each.
  const bf16_t* pA[4];
  const bf16_t* pB[4];
#pragma unroll
  for (int j = 0; j < 4; ++j) {
    const int c = j * 256 + wv * 64 + lane;
    const int r = c >> 3, sw = (c & 7) ^ (r & 7);
    pA[j] = Lr.A  + (size_t)(rowBase + r) * K + sw * 8;
    pB[j] = Lr.Bt + (size_t)(colBase + r) * K + sw * 8;
  }

  // ---- read-side swizzled byte offsets ----
  // A-frag for (m, kk): row = wr*64 + m*32 + lo5, chunk = kk*2 + g
  // B-frag for (n, kk): row = wc*64 + n*32 + lo5, chunk = kk*2 + g
  int aoff[2][4], boff[2][4];
#pragma unroll
  for (int m = 0; m < 2; ++m) {
    const int row = wr * 64 + m * 32 + lo5;
#pragma unroll
    for (int kk = 0; kk < 4; ++kk)
      aoff[m][kk] = row * 128 + (((kk * 2 + g) ^ (row & 7)) << 4);
  }
#pragma unroll
  for (int n = 0; n < 2; ++n) {
    const int row = wc * 64 + n * 32 + lo5;
#pragma unroll
    for (int kk = 0; kk < 4; ++kk)
      boff[n][kk] = row * 128 + (((kk * 2 + g) ^ (row & 7)) << 4);
  }

  const int waveB = wv * 1024;
  const int nkt = K >> 6;   // >= 16 for all layers

  // prologue: stage tile 0 into half 0 (8 loads/wave: 4 A + 4 B)
#pragma unroll
  for (int j = 0; j < 4; ++j) {
    gload_lds16(pA[j], AsB + j * 4096 + waveB);
    gload_lds16(pB[j], BsB + j * 4096 + waveB);
  }
  __syncthreads();

  int cur = 0;   // byte offset of current half (0 / 16384)
  for (int kt = 0; kt < nkt; ++kt) {
    if (kt + 1 < nkt) {
      const int ke = (kt + 1) * 64;
      const int nxt = cur ^ 16384;
#pragma unroll
      for (int j = 0; j < 4; ++j) {
        gload_lds16(pA[j] + ke, AsB + nxt + j * 4096 + waveB);
        gload_lds16(pB[j] + ke, BsB + nxt + j * 4096 + waveB);
      }
    }

    bf16x8 a[2][4], b[2][4];
#pragma unroll
    for (int m = 0; m < 2; ++m)
#pragma unroll
      for (int kk = 0; kk < 4; ++kk)
        a[m][kk] = *(const bf16x8*)(AsB + cur + aoff[m][kk]);
#pragma unroll
    for (int n = 0; n < 2; ++n)
#pragma unroll
      for (int kk = 0; kk < 4; ++kk)
        b[n][kk] = *(const bf16x8*)(BsB + cur + boff[n][kk]);

#pragma unroll
    for (int kk = 0; kk < 4; ++kk)
#pragma unroll
      for (int m = 0; m < 2; ++m)
#pragma unroll
        for (int n = 0; n < 2; ++n)
          acc[m][n] = __builtin_amdgcn_mfma_f32_32x32x16_bf16(a[m][kk], b[n][kk], acc[m][n], 0, 0, 0);

    if (kt + 1 < nkt) {
      __syncthreads();   // drains vmcnt (next tile) + lgkm; one barrier per K-step
      cur ^= 16384;
    }
  }

  // epilogue — 32x32 C/D layout: col = lane&31, row = (r&3) + 8*(r>>2) + 4*(lane>>5)
  const int N = Lr.N;
#pragma unroll
  for (int m = 0; m < 2; ++m) {
#pragma unroll
    for (int n = 0; n < 2; ++n) {
      const int row0 = rowBase + wr * 64 + m * 32 + 4 * g;
      const int col  = colBase + wc * 64 + n * 32 + lo5;
#pragma unroll
      for (int r = 0; r < 16; ++r) {
        const int row = row0 + (r & 3) + 8 * (r >> 2);
        const float v = acc[m][n][r];
        const size_t iN = (size_t)row * N + col;
        const size_t iO = (size_t)row * Lr.ostride + col;
        if (Lr.mode == 0) {
          const float mu = Lr.X[iN];
          const float t  = tanhf(v);
          const float e  = mu - t;
          Lr.O1[iO] = e;
          Lr.O2[iN] = __float2bfloat16(e * (1.0f - t * t));
        } else if (Lr.mode == 1) {
          const float e = Lr.X[iN] - v;
          Lr.O1[iO] = e;
          Lr.O2[iN] = __float2bfloat16(e);
        } else if (Lr.mode == 2) {
          const float mu = Lr.X[iN];
          const float nv = mu + MU_DT * (v - mu);
          Lr.O1[iN] = nv;
          Lr.O2[iN] = __float2bfloat16(nv);
        } else {
          const float mu = Lr.X[iN];
          const float e  = Lr.E[iN];
          const float nv = mu + MU_DT * (v - e);
          Lr.O1[iN] = nv;
          Lr.O2[iN] = __float2bfloat16(nv);
        }
      }
    }
  }
}

// convert W (R x C f32) -> Wb (R x C bf16) and WTb (C x R bf16)
__global__ void prep_weight(const float* __restrict__ W, bf16_t* __restrict__ Wb,
                            bf16_t* __restrict__ WTb, int R, int C) {
  __shared__ bf16_t t[64][65];
  const int tx = threadIdx.x, ty = threadIdx.y;  // (64,4)
  const int c0 = blockIdx.x * 64, r0 = blockIdx.y * 64;
  for (int rr = ty; rr < 64; rr += 4) {
    const float v = W[(size_t)(r0 + rr) * C + c0 + tx];
    const bf16_t b = __float2bfloat16(v);
    Wb[(size_t)(r0 + rr) * C + c0 + tx] = b;
    t[rr][tx] = b;
  }
  __syncthreads();
  for (int rr = ty; rr < 64; rr += 4) {
    WTb[(size_t)(c0 + rr) * R + r0 + tx] = t[tx][rr];
  }
}

__global__ void copy_cast(const float* __restrict__ in, float* __restrict__ of,
                          bf16_t* __restrict__ ob, int n) {
  const int i = blockIdx.x * blockDim.x + threadIdx.x;
  if (i < n) {
    const float v = in[i];
    of[i] = v;
    ob[i] = __float2bfloat16(v);
  }
}

__global__ void copy_e0(const float* __restrict__ mu0, float* __restrict__ out) {
  const int i = blockIdx.x * blockDim.x + threadIdx.x;
  if (i < 512 * 1024) {
    const int b = i >> 10, j = i & 1023;
    out[(size_t)b * 12288 + j] = mu0[i];
  }
}

extern "C" void kernel_launch(void* const* d_in, const int* in_sizes, int n_in,
                              void* d_out, int out_size, void* d_ws, size_t ws_size,
                              hipStream_t stream) {
  const float* img  = (const float*)d_in[0];
  const float* mu0i = (const float*)d_in[1];
  const float* mu1i = (const float*)d_in[2];
  const float* mu2i = (const float*)d_in[3];
  const float* W0   = (const float*)d_in[4];
  const float* W1   = (const float*)d_in[5];
  const float* W2   = (const float*)d_in[6];
  float* out = (float*)d_out;
  const int n_iters = 20;  // fixed by setup_inputs

  // ---- workspace carve (all offsets 256B aligned) ----
  char* p = (char*)d_ws;
  auto alloc = [&](size_t bytes) -> char* {
    char* r = p;
    p += (bytes + 255) & ~(size_t)255;
    return r;
  };
  bf16_t* Wb0 = (bf16_t*)alloc((size_t)1024 * 4096 * 2);
  bf16_t* Wb1 = (bf16_t*)alloc((size_t)4096 * 4096 * 2);
  bf16_t* Wb2 = (bf16_t*)alloc((size_t)4096 * 3072 * 2);
  bf16_t* WT0 = (bf16_t*)alloc((size_t)4096 * 1024 * 2);
  bf16_t* WT1 = (bf16_t*)alloc((size_t)4096 * 4096 * 2);
  bf16_t* WT2 = (bf16_t*)alloc((size_t)3072 * 4096 * 2);
  float*  mu0 = (float*)alloc((size_t)512 * 1024 * 4);
  float*  mu1 = (float*)alloc((size_t)512 * 4096 * 4);
  float*  mu2 = (float*)alloc((size_t)512 * 4096 * 4);
  bf16_t* mb0 = (bf16_t*)alloc((size_t)512 * 1024 * 2);
  bf16_t* mb1 = (bf16_t*)alloc((size_t)512 * 4096 * 2);
  bf16_t* mb2 = (bf16_t*)alloc((size_t)512 * 4096 * 2);
  float*  e1  = (float*)alloc((size_t)512 * 4096 * 4);
  float*  e2  = (float*)alloc((size_t)512 * 4096 * 4);
  float*  e3  = (float*)alloc((size_t)512 * 3072 * 4);
  bf16_t* G0  = (bf16_t*)alloc((size_t)512 * 4096 * 2);
  bf16_t* G1  = (bf16_t*)alloc((size_t)512 * 4096 * 2);
  bf16_t* G2  = (bf16_t*)alloc((size_t)512 * 3072 * 2);
  (void)ws_size;

  // ---- prep: weights + mus ----
  dim3 tb(64, 4);
  prep_weight<<<dim3(4096 / 64, 1024 / 64), tb, 0, stream>>>(W0, Wb0, WT0, 1024, 4096);
  prep_weight<<<dim3(4096 / 64, 4096 / 64), tb, 0, stream>>>(W1, Wb1, WT1, 4096, 4096);
  prep_weight<<<dim3(3072 / 64, 4096 / 64), tb, 0, stream>>>(W2, Wb2, WT2, 4096, 3072);
  copy_cast<<<(512 * 1024 + 255) / 256, 256, 0, stream>>>(mu0i, mu0, mb0, 512 * 1024);
  copy_cast<<<(512 * 4096 + 255) / 256, 256, 0, stream>>>(mu1i, mu1, mb1, 512 * 4096);
  copy_cast<<<(512 * 4096 + 255) / 256, 256, 0, stream>>>(mu2i, mu2, mb2, 512 * 4096);

  // ---- GEMM argument blocks (BM=128 -> 4 M-tiles) ----
  // forward: h_l = mu_l @ W_l  -> epilogue produces e_{l+1}, G_l
  GemmArgs fa;
  fa.L[0] = { mb0, WT0, mu1, nullptr, e1, G0, 1024, 4096, 4096, 0 };
  fa.L[1] = { mb1, WT1, mu2, nullptr, e2, G1, 4096, 4096, 4096, 0 };
  fa.L[2] = { mb2, WT2, img, nullptr, e3, G2, 4096, 3072, 3072, 1 };
  fa.tn0 = 32; fa.tn1 = 32; fa.tn2 = 24;
  fa.start1 = 4 * 32;             // 128
  fa.start2 = fa.start1 + 4 * 32; // 256
  const int fwdBlocks = fa.start2 + 4 * 24;  // 352

  GemmArgs faF = fa;  // final pass: write errs straight into d_out (stride 12288)
  faF.L[0].O1 = out + 1024; faF.L[0].ostride = 12288;
  faF.L[1].O1 = out + 5120; faF.L[1].ostride = 12288;
  faF.L[2].O1 = out + 9216; faF.L[2].ostride = 12288;

  // backward: back_l = G_l @ W_l^T -> epilogue updates mu_l (f32 + bf16)
  GemmArgs ba;
  ba.L[0] = { G0, Wb0, mu0, nullptr, mu0, mb0, 4096, 1024, 1024, 2 };
  ba.L[1] = { G1, Wb1, mu1, e1,      mu1, mb1, 4096, 4096, 4096, 3 };
  ba.L[2] = { G2, Wb2, mu2, e2,      mu2, mb2, 3072, 4096, 4096, 3 };
  ba.tn0 = 8; ba.tn1 = 32; ba.tn2 = 32;
  ba.start1 = 4 * 8;              // 32
  ba.start2 = ba.start1 + 4 * 32; // 160
  const int bwdBlocks = ba.start2 + 4 * 32;  // 288

  // ---- iterate ----
  for (int it = 0; it < n_iters; ++it) {
    gemm_merged<<<fwdBlocks, 256, 0, stream>>>(fa);
    gemm_merged<<<bwdBlocks, 256, 0, stream>>>(ba);
  }
  // final prediction/error pass + e0 = mu0
  gemm_merged<<<fwdBlocks, 256, 0, stream>>>(faF);
  copy_e0<<<(512 * 1024 + 255) / 256, 256, 0, stream>>>(mu0, out);
}

// Round 8
// 2542.920 us; speedup vs baseline: 1.6103x; 1.6103x over previous
//
#include <hip/hip_runtime.h>
#include <hip/hip_bf16.h>
#include <stdint.h>

typedef __hip_bfloat16 bf16_t;
typedef __attribute__((ext_vector_type(8))) short bf16x8;
typedef __attribute__((ext_vector_type(4))) float f32x4;

#define MU_DT 0.01f

__device__ inline void gload_lds16(const void* g, void* lds) {
  __builtin_amdgcn_global_load_lds((const __attribute__((address_space(1))) void*)g,
                                   (__attribute__((address_space(3))) void*)lds, 16, 0, 0);
}

// mode: 0 = forward tanh layer, 1 = forward identity (last) layer,
//       2 = backward layer 0 (e0 == mu0), 3 = backward layer >0
struct GemmLayer {
  const bf16_t* A;    // (512 x K) bf16, row-major
  const bf16_t* Bt;   // (N x K) bf16, row-major  ("B^T layout" operand)
  const float*  X;    // fwd: mu_{l+1} or img (512 x N); bwd: mu_l (512 x N)
  const float*  E;    // bwd l>0: e_l (512 x N); else unused
  float*        O1;   // fwd: e_{l+1} out (stride ostride); bwd: mu_l out (f32)
  bf16_t*       O2;   // fwd: G_l out (bf16, 512 x N); bwd: mub_l out (bf16)
  int K, N, ostride, mode;
};

struct GemmArgs {
  GemmLayer L[3];
  int start1, start2;     // flat block-id starts of layer 1 and layer 2
  int tn0, tn1, tn2;      // tiles along N per layer
};

// BM=64 x BN=128, BK=64, EIGHT waves (512 thr), per-wave 32x32 output
// (2x2 of 16x16x32). Rationale (R7 post-mortem): kernel is LATENCY-bound,
// not LDS-throughput-bound — R7's 2x FLOP/LDS-byte gave zero per-block gain.
// So maximize resident waves: 8 waves/block x 3 blocks/CU (48KiB LDS) ~22
// waves/CU, 2x the R4 structure, same 704/576-block grid (92% makespan).
//
// Schedule (R4, proven): issue next-tile global_load_lds FIRST, then
// ds_read+MFMA on current half, then ONE __syncthreads per K-step.
//
// Grid mapping: local = tm*tilesN + tn (tn FASTEST). With round-robin
// block->XCD dispatch (XCD = bid%8) and tilesN a multiple of 8, the 8
// M-tile sharers of B-panel tn land on the SAME XCD -> B fetched once per
// L2. (R5's tm-fastest tripled FETCH_SIZE. Keep this.)
//
// Swizzle: LDS rows 128B = 8 x 16B slots, slot ^= (row&7), applied on the
// global SOURCE address (LDS stays linear for global_load_lds) and again
// on the ds_read side (rule #21). 16-lane cohorts -> 2-way only (free).
__global__ __launch_bounds__(512) void gemm_merged(GemmArgs args) {
  __shared__ __align__(16) bf16_t As[2 * 64 * 64];    // 2 x 8 KiB
  __shared__ __align__(16) bf16_t Bs[2 * 128 * 64];   // 2 x 16 KiB

  const int bid = blockIdx.x;
  int l, local, tilesN;
  if (bid >= args.start2)      { l = 2; local = bid - args.start2; tilesN = args.tn2; }
  else if (bid >= args.start1) { l = 1; local = bid - args.start1; tilesN = args.tn1; }
  else                         { l = 0; local = bid;               tilesN = args.tn0; }
  const GemmLayer Lr = args.L[l];
  const int tm = local / tilesN;
  const int tn = local % tilesN;
  const int K = Lr.K;
  const int rowBase = tm * 64;
  const int colBase = tn * 128;

  const int tid  = threadIdx.x;        // 0..511
  const int lane = tid & 63;
  const int wv   = tid >> 6;           // 0..7
  const int wrM  = wv >> 2;            // 0..1 -> 32-row band
  const int wcN  = wv & 3;             // 0..3 -> 32-col band
  const int lo   = lane & 15, hi = lane >> 4;

  f32x4 acc[2][2];
#pragma unroll
  for (int m = 0; m < 2; ++m)
#pragma unroll
    for (int n = 0; n < 2; ++n)
      acc[m][n] = f32x4{0.f, 0.f, 0.f, 0.f};

  char* AsB = (char*)As;   // halves at +0 / +8192
  char* BsB = (char*)Bs;   // halves at +0 / +16384

  // ---- staging precompute: per 16B-chunk c -> (row = c>>3, slot = c&7) ----
  // A tile: 64x64 bf16 = 512 chunks (1/thread). B tile: 1024 chunks (2/thread).
  const bf16_t* pA0;
  const bf16_t* pB[2];
  {
    const int c = tid;
    const int r = c >> 3, sw = (c & 7) ^ (r & 7);
    pA0 = Lr.A + (size_t)(rowBase + r) * K + sw * 8;
  }
#pragma unroll
  for (int j = 0; j < 2; ++j) {
    const int c = j * 512 + tid;
    const int r = c >> 3, sw = (c & 7) ^ (r & 7);
    pB[j] = Lr.Bt + (size_t)(colBase + r) * K + sw * 8;
  }

  // ---- read-side swizzled byte offsets ----
  int aoff[2][2], boff[2][2];
#pragma unroll
  for (int m = 0; m < 2; ++m) {
    const int row = wrM * 32 + m * 16 + lo;
#pragma unroll
    for (int kk = 0; kk < 2; ++kk)
      aoff[m][kk] = row * 128 + (((kk * 4 + hi) ^ (row & 7)) << 4);
  }
#pragma unroll
  for (int n = 0; n < 2; ++n) {
    const int row = wcN * 32 + n * 16 + lo;
#pragma unroll
    for (int kk = 0; kk < 2; ++kk)
      boff[n][kk] = row * 128 + (((kk * 4 + hi) ^ (row & 7)) << 4);
  }

  const int waveB = wv * 1024;
  const int nkt = K >> 6;   // >= 16 for all layers

  // prologue: stage tile 0 into half 0 (3 loads/thread: 1 A + 2 B)
  gload_lds16(pA0,   AsB + waveB);
  gload_lds16(pB[0], BsB + waveB);
  gload_lds16(pB[1], BsB + 8192 + waveB);
  __syncthreads();

  int cur = 0;   // 0 / 1
  for (int kt = 0; kt < nkt; ++kt) {
    const int curA = cur * 8192, curB = cur * 16384;
    if (kt + 1 < nkt) {
      const int ke = (kt + 1) * 64;
      gload_lds16(pA0 + ke,   AsB + (curA ^ 8192) + waveB);
      gload_lds16(pB[0] + ke, BsB + (curB ^ 16384) + waveB);
      gload_lds16(pB[1] + ke, BsB + (curB ^ 16384) + 8192 + waveB);
    }

    bf16x8 a[2][2], b[2][2];
#pragma unroll
    for (int m = 0; m < 2; ++m)
#pragma unroll
      for (int kk = 0; kk < 2; ++kk)
        a[m][kk] = *(const bf16x8*)(AsB + curA + aoff[m][kk]);
#pragma unroll
    for (int n = 0; n < 2; ++n)
#pragma unroll
      for (int kk = 0; kk < 2; ++kk)
        b[n][kk] = *(const bf16x8*)(BsB + curB + boff[n][kk]);

#pragma unroll
    for (int kk = 0; kk < 2; ++kk)
#pragma unroll
      for (int m = 0; m < 2; ++m)
#pragma unroll
        for (int n = 0; n < 2; ++n)
          acc[m][n] = __builtin_amdgcn_mfma_f32_16x16x32_bf16(a[m][kk], b[n][kk], acc[m][n], 0, 0, 0);

    if (kt + 1 < nkt) {
      __syncthreads();   // drains vmcnt (next tile) + lgkm; one barrier per K-step
      cur ^= 1;
    }
  }

  // epilogue — C/D layout: col = lane&15, row = (lane>>4)*4 + reg
  const int N = Lr.N;
#pragma unroll
  for (int m = 0; m < 2; ++m) {
#pragma unroll
    for (int n = 0; n < 2; ++n) {
#pragma unroll
      for (int r = 0; r < 4; ++r) {
        const int row = rowBase + wrM * 32 + m * 16 + hi * 4 + r;
        const int col = colBase + wcN * 32 + n * 16 + lo;
        const float v = acc[m][n][r];
        const size_t iN = (size_t)row * N + col;
        const size_t iO = (size_t)row * Lr.ostride + col;
        if (Lr.mode == 0) {
          const float mu = Lr.X[iN];
          const float t  = tanhf(v);
          const float e  = mu - t;
          Lr.O1[iO] = e;
          Lr.O2[iN] = __float2bfloat16(e * (1.0f - t * t));
        } else if (Lr.mode == 1) {
          const float e = Lr.X[iN] - v;
          Lr.O1[iO] = e;
          Lr.O2[iN] = __float2bfloat16(e);
        } else if (Lr.mode == 2) {
          const float mu = Lr.X[iN];
          const float nv = mu + MU_DT * (v - mu);
          Lr.O1[iN] = nv;
          Lr.O2[iN] = __float2bfloat16(nv);
        } else {
          const float mu = Lr.X[iN];
          const float e  = Lr.E[iN];
          const float nv = mu + MU_DT * (v - e);
          Lr.O1[iN] = nv;
          Lr.O2[iN] = __float2bfloat16(nv);
        }
      }
    }
  }
}

// convert W (R x C f32) -> Wb (R x C bf16) and WTb (C x R bf16)
__global__ void prep_weight(const float* __restrict__ W, bf16_t* __restrict__ Wb,
                            bf16_t* __restrict__ WTb, int R, int C) {
  __shared__ bf16_t t[64][65];
  const int tx = threadIdx.x, ty = threadIdx.y;  // (64,4)
  const int c0 = blockIdx.x * 64, r0 = blockIdx.y * 64;
  for (int rr = ty; rr < 64; rr += 4) {
    const float v = W[(size_t)(r0 + rr) * C + c0 + tx];
    const bf16_t b = __float2bfloat16(v);
    Wb[(size_t)(r0 + rr) * C + c0 + tx] = b;
    t[rr][tx] = b;
  }
  __syncthreads();
  for (int rr = ty; rr < 64; rr += 4) {
    WTb[(size_t)(c0 + rr) * R + r0 + tx] = t[tx][rr];
  }
}

__global__ void copy_cast(const float* __restrict__ in, float* __restrict__ of,
                          bf16_t* __restrict__ ob, int n) {
  const int i = blockIdx.x * blockDim.x + threadIdx.x;
  if (i < n) {
    const float v = in[i];
    of[i] = v;
    ob[i] = __float2bfloat16(v);
  }
}

__global__ void copy_e0(const float* __restrict__ mu0, float* __restrict__ out) {
  const int i = blockIdx.x * blockDim.x + threadIdx.x;
  if (i < 512 * 1024) {
    const int b = i >> 10, j = i & 1023;
    out[(size_t)b * 12288 + j] = mu0[i];
  }
}

extern "C" void kernel_launch(void* const* d_in, const int* in_sizes, int n_in,
                              void* d_out, int out_size, void* d_ws, size_t ws_size,
                              hipStream_t stream) {
  const float* img  = (const float*)d_in[0];
  const float* mu0i = (const float*)d_in[1];
  const float* mu1i = (const float*)d_in[2];
  const float* mu2i = (const float*)d_in[3];
  const float* W0   = (const float*)d_in[4];
  const float* W1   = (const float*)d_in[5];
  const float* W2   = (const float*)d_in[6];
  float* out = (float*)d_out;
  const int n_iters = 20;  // fixed by setup_inputs

  // ---- workspace carve (all offsets 256B aligned) ----
  char* p = (char*)d_ws;
  auto alloc = [&](size_t bytes) -> char* {
    char* r = p;
    p += (bytes + 255) & ~(size_t)255;
    return r;
  };
  bf16_t* Wb0 = (bf16_t*)alloc((size_t)1024 * 4096 * 2);
  bf16_t* Wb1 = (bf16_t*)alloc((size_t)4096 * 4096 * 2);
  bf16_t* Wb2 = (bf16_t*)alloc((size_t)4096 * 3072 * 2);
  bf16_t* WT0 = (bf16_t*)alloc((size_t)4096 * 1024 * 2);
  bf16_t* WT1 = (bf16_t*)alloc((size_t)4096 * 4096 * 2);
  bf16_t* WT2 = (bf16_t*)alloc((size_t)3072 * 4096 * 2);
  float*  mu0 = (float*)alloc((size_t)512 * 1024 * 4);
  float*  mu1 = (float*)alloc((size_t)512 * 4096 * 4);
  float*  mu2 = (float*)alloc((size_t)512 * 4096 * 4);
  bf16_t* mb0 = (bf16_t*)alloc((size_t)512 * 1024 * 2);
  bf16_t* mb1 = (bf16_t*)alloc((size_t)512 * 4096 * 2);
  bf16_t* mb2 = (bf16_t*)alloc((size_t)512 * 4096 * 2);
  float*  e1  = (float*)alloc((size_t)512 * 4096 * 4);
  float*  e2  = (float*)alloc((size_t)512 * 4096 * 4);
  float*  e3  = (float*)alloc((size_t)512 * 3072 * 4);
  bf16_t* G0  = (bf16_t*)alloc((size_t)512 * 4096 * 2);
  bf16_t* G1  = (bf16_t*)alloc((size_t)512 * 4096 * 2);
  bf16_t* G2  = (bf16_t*)alloc((size_t)512 * 3072 * 2);
  (void)ws_size;

  // ---- prep: weights + mus ----
  dim3 tb(64, 4);
  prep_weight<<<dim3(4096 / 64, 1024 / 64), tb, 0, stream>>>(W0, Wb0, WT0, 1024, 4096);
  prep_weight<<<dim3(4096 / 64, 4096 / 64), tb, 0, stream>>>(W1, Wb1, WT1, 4096, 4096);
  prep_weight<<<dim3(3072 / 64, 4096 / 64), tb, 0, stream>>>(W2, Wb2, WT2, 4096, 3072);
  copy_cast<<<(512 * 1024 + 255) / 256, 256, 0, stream>>>(mu0i, mu0, mb0, 512 * 1024);
  copy_cast<<<(512 * 4096 + 255) / 256, 256, 0, stream>>>(mu1i, mu1, mb1, 512 * 4096);
  copy_cast<<<(512 * 4096 + 255) / 256, 256, 0, stream>>>(mu2i, mu2, mb2, 512 * 4096);

  // ---- GEMM argument blocks (BM=64 -> 8 M-tiles) ----
  // forward: h_l = mu_l @ W_l  -> epilogue produces e_{l+1}, G_l
  GemmArgs fa;
  fa.L[0] = { mb0, WT0, mu1, nullptr, e1, G0, 1024, 4096, 4096, 0 };
  fa.L[1] = { mb1, WT1, mu2, nullptr, e2, G1, 4096, 4096, 4096, 0 };
  fa.L[2] = { mb2, WT2, img, nullptr, e3, G2, 4096, 3072, 3072, 1 };
  fa.tn0 = 32; fa.tn1 = 32; fa.tn2 = 24;
  fa.start1 = 8 * 32;             // 256
  fa.start2 = fa.start1 + 8 * 32; // 512
  const int fwdBlocks = fa.start2 + 8 * 24;  // 704

  GemmArgs faF = fa;  // final pass: write errs straight into d_out (stride 12288)
  faF.L[0].O1 = out + 1024; faF.L[0].ostride = 12288;
  faF.L[1].O1 = out + 5120; faF.L[1].ostride = 12288;
  faF.L[2].O1 = out + 9216; faF.L[2].ostride = 12288;

  // backward: back_l = G_l @ W_l^T -> epilogue updates mu_l (f32 + bf16)
  GemmArgs ba;
  ba.L[0] = { G0, Wb0, mu0, nullptr, mu0, mb0, 4096, 1024, 1024, 2 };
  ba.L[1] = { G1, Wb1, mu1, e1,      mu1, mb1, 4096, 4096, 4096, 3 };
  ba.L[2] = { G2, Wb2, mu2, e2,      mu2, mb2, 3072, 4096, 4096, 3 };
  ba.tn0 = 8; ba.tn1 = 32; ba.tn2 = 32;
  ba.start1 = 8 * 8;              // 64
  ba.start2 = ba.start1 + 8 * 32; // 320
  const int bwdBlocks = ba.start2 + 8 * 32;  // 576

  // ---- iterate ----
  for (int it = 0; it < n_iters; ++it) {
    gemm_merged<<<fwdBlocks, 512, 0, stream>>>(fa);
    gemm_merged<<<bwdBlocks, 512, 0, stream>>>(ba);
  }
  // final prediction/error pass + e0 = mu0
  gemm_merged<<<fwdBlocks, 512, 0, stream>>>(faF);
  copy_e0<<<(512 * 1024 + 255) / 256, 256, 0, stream>>>(mu0, out);
}